// Round 2
// baseline (132.479 us; speedup 1.0000x reference)
//
#include <hip/hip_runtime.h>
#include <math.h>

// Problem constants
#define Bsz 64
#define IC  512   // in_caps
#define KD  128   // in_dim
#define NC  32    // num_caps
#define DC  32    // dim_caps
#define CHUNK 64  // in_caps per block
#define NCH   8   // IC / CHUNK
#define NBLK  512 // Bsz * NCH
#define NTHR  256

#define CSTR 36   // padded row stride (floats); 144B rows, 16B-aligned

// workspace layout (floats)
#define CXP_SZ (Bsz * NCH * NC * KD)   // 2,097,152 floats (8 MB)   cx partials [b][ch][n][k]
#define WV_SZ  (Bsz * NC * KD)         //   262,144 floats (1 MB)   wv [b][n][k]
#define BB_SZ  (Bsz * NC * IC)         // 1,048,576 floats (4 MB)   routing logits [b][n][i]

// x_s storage: row i holds k-quads rotated by (i>>2): quad' = (quad + (i>>2)) & 31
__device__ __forceinline__ int xaddr(int i, int kq) {
    return i * KD + ((((kq) + (i >> 2)) & 31) << 2);
}

// ---------------- Kernel A: softmax over n + cx partials ----------------
// block = (b, ch). Reads bb_in[b][n][chunk], x[b][chunk]; writes cxp[b][ch][n][k].
__global__ __launch_bounds__(NTHR)
void kA(const float* __restrict__ bb_in, const float* __restrict__ x_g,
        float* __restrict__ cxp)
{
    __shared__ float x_s[CHUNK * KD];      // 32 KB, quad-rotated
    __shared__ float bb_s[NC][CHUNK];      // 8 KB
    __shared__ float c_sT[CHUNK * CSTR];   // 9 KB, c transposed [i][n]

    const int t = threadIdx.x, blk = blockIdx.x;
    const int b = blk >> 3, ch = blk & 7, i0g = ch * CHUNK;

    for (int rep = 0; rep < 8; ++rep) {
        int v = t + rep * NTHR;            // float4 idx 0..2047
        int i = v >> 5, kq = v & 31;
        float4 val = *(const float4*)(x_g + ((size_t)(b * IC + i0g + i)) * KD + (kq << 2));
        *(float4*)(x_s + xaddr(i, kq)) = val;
    }
    for (int rep = 0; rep < 2; ++rep) {
        int v = t + rep * NTHR;            // 0..511
        int n = v >> 4, i4 = v & 15;
        *(float4*)(&bb_s[n][i4 << 2]) =
            *(const float4*)(bb_in + ((size_t)(b * NC + n)) * IC + i0g + (i4 << 2));
    }
    __syncthreads();

    if (t < CHUNK) {
        const int ii = t;
        float m = -1e30f;
        #pragma unroll
        for (int n = 0; n < NC; ++n) m = fmaxf(m, bb_s[n][ii]);
        float e[NC]; float sum = 0.f;
        #pragma unroll
        for (int n = 0; n < NC; ++n) { float ev = __expf(bb_s[n][ii] - m); e[n] = ev; sum += ev; }
        const float inv = 1.f / sum;
        float* crow = c_sT + ii * CSTR;
        #pragma unroll
        for (int n = 0; n < NC; ++n) crow[n] = e[n] * inv;
    }
    __syncthreads();

    // cx = C @ X  (32n x 128k, reduce over 64 i); each thread: 4n x 4k tile
    const int tn = t & 7, tk = t >> 3;
    const int n0 = tn << 2;
    float4 acc0 = {0,0,0,0}, acc1 = {0,0,0,0}, acc2 = {0,0,0,0}, acc3 = {0,0,0,0};
    for (int ii = 0; ii < CHUNK; ++ii) {
        const float4 c4 = *(const float4*)(c_sT + ii * CSTR + n0);
        const float4 x4 = *(const float4*)(x_s + xaddr(ii, tk));
        acc0.x += c4.x*x4.x; acc0.y += c4.x*x4.y; acc0.z += c4.x*x4.z; acc0.w += c4.x*x4.w;
        acc1.x += c4.y*x4.x; acc1.y += c4.y*x4.y; acc1.z += c4.y*x4.z; acc1.w += c4.y*x4.w;
        acc2.x += c4.z*x4.x; acc2.y += c4.z*x4.y; acc2.z += c4.z*x4.z; acc2.w += c4.z*x4.w;
        acc3.x += c4.w*x4.x; acc3.y += c4.w*x4.y; acc3.z += c4.w*x4.z; acc3.w += c4.w*x4.w;
    }
    float* base = cxp + ((size_t)(b * NCH + ch)) * NC * KD + (tk << 2);
    *(float4*)(base + (size_t)(n0 + 0) * KD) = acc0;
    *(float4*)(base + (size_t)(n0 + 1) * KD) = acc1;
    *(float4*)(base + (size_t)(n0 + 2) * KD) = acc2;
    *(float4*)(base + (size_t)(n0 + 3) * KD) = acc3;
}

// ---------------- Kernel B: reduce partials, s = cx@W[n], squash, wv or out ----------------
// block = (group-of-4 b, n).
__global__ __launch_bounds__(NTHR)
void kB(const float* __restrict__ cxp, const float* __restrict__ W_g,
        float* __restrict__ wv_g, float* __restrict__ out_g, int final_)
{
    __shared__ float w_s[KD * DC];         // 16 KB, W[n] layout [k][d]
    __shared__ float cxs[4 * KD];          // 2 KB
    __shared__ float vs_s[4][DC];

    const int t = threadIdx.x, blk = blockIdx.x;
    const int pb_n = blk & 31, pb_b0 = (blk >> 5) * 4;

    for (int rep = 0; rep < 4; ++rep) {
        int v = t + rep * NTHR;            // float4 idx 0..1023
        *(float4*)(w_s + (v << 2)) = *(const float4*)(W_g + (size_t)pb_n * KD * DC + (v << 2));
    }
    if (t < 128) {
        const int bsub = t >> 5, k4 = t & 31;
        float4 s4 = {0,0,0,0};
        const float* p = cxp + (((size_t)(pb_b0 + bsub) * NCH) * NC + pb_n) * KD + (k4 << 2);
        #pragma unroll
        for (int c2 = 0; c2 < NCH; ++c2) {
            float4 v4 = *(const float4*)(p + (size_t)c2 * NC * KD);
            s4.x += v4.x; s4.y += v4.y; s4.z += v4.z; s4.w += v4.w;
        }
        *(float4*)(cxs + bsub * KD + (k4 << 2)) = s4;
    }
    __syncthreads();

    if (t < 128) {
        const int bsub = t >> 5, d = t & 31;
        float s = 0.f;
        const float* crow = cxs + bsub * KD;
        for (int k = 0; k < KD; ++k) s += crow[k] * w_s[k * DC + d];
        float sn = s * s;
        #pragma unroll
        for (int off = 1; off < 32; off <<= 1) sn += __shfl_xor(sn, off, 64);
        const float vv = s * (sn / ((1.f + sn) * (sqrtf(sn) + 1e-8f)));
        if (final_) {
            out_g[((size_t)(pb_b0 + bsub) * NC + pb_n) * DC + d] = vv;
        } else {
            vs_s[bsub][d] = vv;
        }
    }
    if (!final_) {
        __syncthreads();
        // wv[k] = sum_d W[k][d] * v[d], for 4 b's
        const int bsub = t >> 6, kk = t & 63;
        for (int k = kk; k < KD; k += 64) {
            float acc = 0.f;
            const float* wrow = w_s + k * DC;
            const float* vrow = &vs_s[bsub][0];
            #pragma unroll
            for (int d = 0; d < DC; ++d) acc += wrow[d] * vrow[d];
            wv_g[((size_t)(pb_b0 + bsub) * NC + pb_n) * KD + k] = acc;
        }
    }
}

// ---------------- Kernel C: uv = wv @ X^T ; bb_out = bb_in + uv ----------------
// block = (b, ch).
__global__ __launch_bounds__(NTHR)
void kC(const float* __restrict__ bb_in, const float* __restrict__ x_g,
        const float* __restrict__ wv_g, float* __restrict__ bb_out)
{
    __shared__ float x_s[CHUNK * KD];      // 32 KB, quad-rotated
    __shared__ float bb_s[NC][CHUNK];      // 8 KB
    __shared__ float wv_sT[KD * CSTR];     // 18 KB, [k][n]

    const int t = threadIdx.x, blk = blockIdx.x;
    const int b = blk >> 3, ch = blk & 7, i0g = ch * CHUNK;

    for (int rep = 0; rep < 8; ++rep) {
        int v = t + rep * NTHR;
        int i = v >> 5, kq = v & 31;
        float4 val = *(const float4*)(x_g + ((size_t)(b * IC + i0g + i)) * KD + (kq << 2));
        *(float4*)(x_s + xaddr(i, kq)) = val;
    }
    for (int rep = 0; rep < 2; ++rep) {
        int v = t + rep * NTHR;
        int n = v >> 4, i4 = v & 15;
        *(float4*)(&bb_s[n][i4 << 2]) =
            *(const float4*)(bb_in + ((size_t)(b * NC + n)) * IC + i0g + (i4 << 2));
    }
    for (int rep = 0; rep < 4; ++rep) {
        const int n = t & 31;
        const int k4 = (t >> 5) + (rep << 3);   // 0..31
        float4 v4 = *(const float4*)(wv_g + ((size_t)(b * NC) + n) * KD + (k4 << 2));
        wv_sT[(k4 * 4 + 0) * CSTR + n] = v4.x;
        wv_sT[(k4 * 4 + 1) * CSTR + n] = v4.y;
        wv_sT[(k4 * 4 + 2) * CSTR + n] = v4.z;
        wv_sT[(k4 * 4 + 3) * CSTR + n] = v4.w;
    }
    __syncthreads();

    if (t < 128) {
        const int tn = t & 7, ti = t >> 3;     // tile: 4n x 4i
        const int n0 = tn << 2, i0 = ti << 2;
        float4 a0 = {0,0,0,0}, a1 = {0,0,0,0}, a2 = {0,0,0,0}, a3 = {0,0,0,0};
        for (int kq = 0; kq < 32; ++kq) {
            const float4 xr0 = *(const float4*)(x_s + xaddr(i0 + 0, kq));
            const float4 xr1 = *(const float4*)(x_s + xaddr(i0 + 1, kq));
            const float4 xr2 = *(const float4*)(x_s + xaddr(i0 + 2, kq));
            const float4 xr3 = *(const float4*)(x_s + xaddr(i0 + 3, kq));
            const float4 w0 = *(const float4*)(wv_sT + (kq * 4 + 0) * CSTR + n0);
            const float4 w1 = *(const float4*)(wv_sT + (kq * 4 + 1) * CSTR + n0);
            const float4 w2 = *(const float4*)(wv_sT + (kq * 4 + 2) * CSTR + n0);
            const float4 w3 = *(const float4*)(wv_sT + (kq * 4 + 3) * CSTR + n0);
            a0.x += xr0.x*w0.x + xr0.y*w1.x + xr0.z*w2.x + xr0.w*w3.x;
            a0.y += xr0.x*w0.y + xr0.y*w1.y + xr0.z*w2.y + xr0.w*w3.y;
            a0.z += xr0.x*w0.z + xr0.y*w1.z + xr0.z*w2.z + xr0.w*w3.z;
            a0.w += xr0.x*w0.w + xr0.y*w1.w + xr0.z*w2.w + xr0.w*w3.w;
            a1.x += xr1.x*w0.x + xr1.y*w1.x + xr1.z*w2.x + xr1.w*w3.x;
            a1.y += xr1.x*w0.y + xr1.y*w1.y + xr1.z*w2.y + xr1.w*w3.y;
            a1.z += xr1.x*w0.z + xr1.y*w1.z + xr1.z*w2.z + xr1.w*w3.z;
            a1.w += xr1.x*w0.w + xr1.y*w1.w + xr1.z*w2.w + xr1.w*w3.w;
            a2.x += xr2.x*w0.x + xr2.y*w1.x + xr2.z*w2.x + xr2.w*w3.x;
            a2.y += xr2.x*w0.y + xr2.y*w1.y + xr2.z*w2.y + xr2.w*w3.y;
            a2.z += xr2.x*w0.z + xr2.y*w1.z + xr2.z*w2.z + xr2.w*w3.z;
            a2.w += xr2.x*w0.w + xr2.y*w1.w + xr2.z*w2.w + xr2.w*w3.w;
            a3.x += xr3.x*w0.x + xr3.y*w1.x + xr3.z*w2.x + xr3.w*w3.x;
            a3.y += xr3.x*w0.y + xr3.y*w1.y + xr3.z*w2.y + xr3.w*w3.y;
            a3.z += xr3.x*w0.z + xr3.y*w1.z + xr3.z*w2.z + xr3.w*w3.z;
            a3.w += xr3.x*w0.w + xr3.y*w1.w + xr3.z*w2.w + xr3.w*w3.w;
        }
        bb_s[n0+0][i0+0] += a0.x; bb_s[n0+1][i0+0] += a0.y; bb_s[n0+2][i0+0] += a0.z; bb_s[n0+3][i0+0] += a0.w;
        bb_s[n0+0][i0+1] += a1.x; bb_s[n0+1][i0+1] += a1.y; bb_s[n0+2][i0+1] += a1.z; bb_s[n0+3][i0+1] += a1.w;
        bb_s[n0+0][i0+2] += a2.x; bb_s[n0+1][i0+2] += a2.y; bb_s[n0+2][i0+2] += a2.z; bb_s[n0+3][i0+2] += a2.w;
        bb_s[n0+0][i0+3] += a3.x; bb_s[n0+1][i0+3] += a3.y; bb_s[n0+2][i0+3] += a3.z; bb_s[n0+3][i0+3] += a3.w;
    }
    __syncthreads();

    for (int rep = 0; rep < 2; ++rep) {
        int v = t + rep * NTHR;
        int n = v >> 4, i4 = v & 15;
        *(float4*)(bb_out + ((size_t)(b * NC + n)) * IC + i0g + (i4 << 2)) =
            *(const float4*)(&bb_s[n][i4 << 2]);
    }
}

extern "C" void kernel_launch(void* const* d_in, const int* in_sizes, int n_in,
                              void* d_out, int out_size, void* d_ws, size_t ws_size,
                              hipStream_t stream) {
    const float* x  = (const float*)d_in[0];
    const float* W  = (const float*)d_in[1];
    const float* b0 = (const float*)d_in[2];
    float* out = (float*)d_out;

    float* cxp   = (float*)d_ws;                 // 8 MB
    float* wv    = cxp + CXP_SZ;                 // 1 MB
    float* bb_ws = wv + WV_SZ;                   // 4 MB

    // iter 0
    kA<<<NBLK, NTHR, 0, stream>>>(b0, x, cxp);
    kB<<<NBLK, NTHR, 0, stream>>>(cxp, W, wv, out, 0);
    kC<<<NBLK, NTHR, 0, stream>>>(b0, x, wv, bb_ws);
    // iter 1
    kA<<<NBLK, NTHR, 0, stream>>>(bb_ws, x, cxp);
    kB<<<NBLK, NTHR, 0, stream>>>(cxp, W, wv, out, 0);
    kC<<<NBLK, NTHR, 0, stream>>>(bb_ws, x, wv, bb_ws);
    // iter 2 (final)
    kA<<<NBLK, NTHR, 0, stream>>>(bb_ws, x, cxp);
    kB<<<NBLK, NTHR, 0, stream>>>(cxp, W, wv, out, 1);
}

// Round 3
// 126.865 us; speedup vs baseline: 1.0442x; 1.0442x over previous
//
#include <hip/hip_runtime.h>
#include <math.h>

// Problem constants
#define Bsz 64
#define IC  512   // in_caps
#define KD  128   // in_dim
#define NC  32    // num_caps
#define DC  32    // dim_caps
#define CHUNK 64  // in_caps per block
#define NCH   8   // IC / CHUNK
#define NBLK  512 // Bsz * NCH
#define NTHR  256
#define NTHRB 128

#define CSTR 36   // padded stride for c_sT / wv_sT rows (floats); 144B, 16B-aligned
#define BSTR 68   // padded stride for bb_s rows: bank=(4n+4ti+r)%32 -> <=2-way on uv scatter
#define WSTR 33   // padded stride for w_s rows: bank=(k+d)%32 -> conflict-free col+row reads

// workspace layout (floats)
#define CXP_SZ (Bsz * NCH * NC * KD)   // 8 MB   cx partials [b][ch][n][k]
#define WV_SZ  (Bsz * NC * KD)         // 1 MB   wv [b][n][k]

// x_s storage: row i holds k-quads rotated by (i>>2): quad' = (quad + (i>>2)) & 31
__device__ __forceinline__ int xaddr(int i, int kq) {
    return i * KD + ((((kq) + (i >> 2)) & 31) << 2);
}

// ---------------- Kernel ACX: [uv + bb update] + softmax + cx partials ----------------
// block = (b, ch). do_uv: add uv from wv first (iterations 1,2). write_bb: persist bb (iter 1 only).
__global__ __launch_bounds__(NTHR)
void kACX(const float* __restrict__ bb_in, const float* __restrict__ x_g,
          const float* __restrict__ wv_g, float* __restrict__ bb_out,
          float* __restrict__ cxp, int do_uv, int write_bb)
{
    __shared__ float x_s[CHUNK * KD];      // 32 KB, quad-rotated
    __shared__ float bb_s[NC * BSTR];      // 8.5 KB
    __shared__ float scr[KD * CSTR];       // 18 KB union: wv_sT [k][n] then c_sT [i][n]

    const int t = threadIdx.x, blk = blockIdx.x;
    const int b = blk >> 3, ch = blk & 7, i0g = ch * CHUNK;

    // stage x (rotated)
    for (int rep = 0; rep < 8; ++rep) {
        int v = t + rep * NTHR;            // float4 idx 0..2047
        int i = v >> 5, kq = v & 31;
        *(float4*)(x_s + xaddr(i, kq)) =
            *(const float4*)(x_g + ((size_t)(b * IC + i0g + i)) * KD + (kq << 2));
    }
    // stage bb
    for (int rep = 0; rep < 2; ++rep) {
        int v = t + rep * NTHR;            // 0..511
        int n = v >> 4, i4 = v & 15;
        *(float4*)(bb_s + n * BSTR + (i4 << 2)) =
            *(const float4*)(bb_in + ((size_t)(b * NC + n)) * IC + i0g + (i4 << 2));
    }
    if (do_uv) {
        // stage wv transposed: [k][n] with CSTR pad
        for (int rep = 0; rep < 4; ++rep) {
            const int n = t & 31;
            const int k4 = (t >> 5) + (rep << 3);   // 0..31
            float4 v4 = *(const float4*)(wv_g + ((size_t)(b * NC) + n) * KD + (k4 << 2));
            scr[(k4 * 4 + 0) * CSTR + n] = v4.x;
            scr[(k4 * 4 + 1) * CSTR + n] = v4.y;
            scr[(k4 * 4 + 2) * CSTR + n] = v4.z;
            scr[(k4 * 4 + 3) * CSTR + n] = v4.w;
        }
    }
    __syncthreads();

    if (do_uv) {
        // uv = wv @ X^T ; bb += uv   (t<128: 4n x 4i tile each)
        if (t < 128) {
            const int tn = t & 7, ti = t >> 3;
            const int n0 = tn << 2, i0 = ti << 2;
            float4 a0 = {0,0,0,0}, a1 = {0,0,0,0}, a2 = {0,0,0,0}, a3 = {0,0,0,0};
            for (int kq = 0; kq < 32; ++kq) {
                const float4 xr0 = *(const float4*)(x_s + xaddr(i0 + 0, kq));
                const float4 xr1 = *(const float4*)(x_s + xaddr(i0 + 1, kq));
                const float4 xr2 = *(const float4*)(x_s + xaddr(i0 + 2, kq));
                const float4 xr3 = *(const float4*)(x_s + xaddr(i0 + 3, kq));
                const float4 w0 = *(const float4*)(scr + (kq * 4 + 0) * CSTR + n0);
                const float4 w1 = *(const float4*)(scr + (kq * 4 + 1) * CSTR + n0);
                const float4 w2 = *(const float4*)(scr + (kq * 4 + 2) * CSTR + n0);
                const float4 w3 = *(const float4*)(scr + (kq * 4 + 3) * CSTR + n0);
                a0.x += xr0.x*w0.x + xr0.y*w1.x + xr0.z*w2.x + xr0.w*w3.x;
                a0.y += xr0.x*w0.y + xr0.y*w1.y + xr0.z*w2.y + xr0.w*w3.y;
                a0.z += xr0.x*w0.z + xr0.y*w1.z + xr0.z*w2.z + xr0.w*w3.z;
                a0.w += xr0.x*w0.w + xr0.y*w1.w + xr0.z*w2.w + xr0.w*w3.w;
                a1.x += xr1.x*w0.x + xr1.y*w1.x + xr1.z*w2.x + xr1.w*w3.x;
                a1.y += xr1.x*w0.y + xr1.y*w1.y + xr1.z*w2.y + xr1.w*w3.y;
                a1.z += xr1.x*w0.z + xr1.y*w1.z + xr1.z*w2.z + xr1.w*w3.z;
                a1.w += xr1.x*w0.w + xr1.y*w1.w + xr1.z*w2.w + xr1.w*w3.w;
                a2.x += xr2.x*w0.x + xr2.y*w1.x + xr2.z*w2.x + xr2.w*w3.x;
                a2.y += xr2.x*w0.y + xr2.y*w1.y + xr2.z*w2.y + xr2.w*w3.y;
                a2.z += xr2.x*w0.z + xr2.y*w1.z + xr2.z*w2.z + xr2.w*w3.z;
                a2.w += xr2.x*w0.w + xr2.y*w1.w + xr2.z*w2.w + xr2.w*w3.w;
                a3.x += xr3.x*w0.x + xr3.y*w1.x + xr3.z*w2.x + xr3.w*w3.x;
                a3.y += xr3.x*w0.y + xr3.y*w1.y + xr3.z*w2.y + xr3.w*w3.y;
                a3.z += xr3.x*w0.z + xr3.y*w1.z + xr3.z*w2.z + xr3.w*w3.z;
                a3.w += xr3.x*w0.w + xr3.y*w1.w + xr3.z*w2.w + xr3.w*w3.w;
            }
            bb_s[(n0+0)*BSTR + i0+0] += a0.x; bb_s[(n0+1)*BSTR + i0+0] += a0.y;
            bb_s[(n0+2)*BSTR + i0+0] += a0.z; bb_s[(n0+3)*BSTR + i0+0] += a0.w;
            bb_s[(n0+0)*BSTR + i0+1] += a1.x; bb_s[(n0+1)*BSTR + i0+1] += a1.y;
            bb_s[(n0+2)*BSTR + i0+1] += a1.z; bb_s[(n0+3)*BSTR + i0+1] += a1.w;
            bb_s[(n0+0)*BSTR + i0+2] += a2.x; bb_s[(n0+1)*BSTR + i0+2] += a2.y;
            bb_s[(n0+2)*BSTR + i0+2] += a2.z; bb_s[(n0+3)*BSTR + i0+2] += a2.w;
            bb_s[(n0+0)*BSTR + i0+3] += a3.x; bb_s[(n0+1)*BSTR + i0+3] += a3.y;
            bb_s[(n0+2)*BSTR + i0+3] += a3.z; bb_s[(n0+3)*BSTR + i0+3] += a3.w;
        }
        __syncthreads();
        if (write_bb) {
            for (int rep = 0; rep < 2; ++rep) {
                int v = t + rep * NTHR;
                int n = v >> 4, i4 = v & 15;
                *(float4*)(bb_out + ((size_t)(b * NC + n)) * IC + i0g + (i4 << 2)) =
                    *(const float4*)(bb_s + n * BSTR + (i4 << 2));
            }
        }
    }

    // softmax over n for each ii; write c^T into scr
    if (t < CHUNK) {
        const int ii = t;
        float m = -1e30f;
        #pragma unroll
        for (int n = 0; n < NC; ++n) m = fmaxf(m, bb_s[n * BSTR + ii]);
        float e[NC]; float sum = 0.f;
        #pragma unroll
        for (int n = 0; n < NC; ++n) { float ev = __expf(bb_s[n * BSTR + ii] - m); e[n] = ev; sum += ev; }
        const float inv = 1.f / sum;
        float* crow = scr + ii * CSTR;
        #pragma unroll
        for (int n = 0; n < NC; ++n) crow[n] = e[n] * inv;
    }
    __syncthreads();

    // cx = C @ X (32n x 128k over 64 i); each thread 4n x 4k
    const int tn = t & 7, tk = t >> 3;
    const int n0 = tn << 2;
    float4 acc0 = {0,0,0,0}, acc1 = {0,0,0,0}, acc2 = {0,0,0,0}, acc3 = {0,0,0,0};
    for (int ii = 0; ii < CHUNK; ++ii) {
        const float4 c4 = *(const float4*)(scr + ii * CSTR + n0);
        const float4 x4 = *(const float4*)(x_s + xaddr(ii, tk));
        acc0.x += c4.x*x4.x; acc0.y += c4.x*x4.y; acc0.z += c4.x*x4.z; acc0.w += c4.x*x4.w;
        acc1.x += c4.y*x4.x; acc1.y += c4.y*x4.y; acc1.z += c4.y*x4.z; acc1.w += c4.y*x4.w;
        acc2.x += c4.z*x4.x; acc2.y += c4.z*x4.y; acc2.z += c4.z*x4.z; acc2.w += c4.z*x4.w;
        acc3.x += c4.w*x4.x; acc3.y += c4.w*x4.y; acc3.z += c4.w*x4.z; acc3.w += c4.w*x4.w;
    }
    float* base = cxp + ((size_t)(b * NCH + ch)) * NC * KD + (tk << 2);
    *(float4*)(base + (size_t)(n0 + 0) * KD) = acc0;
    *(float4*)(base + (size_t)(n0 + 1) * KD) = acc1;
    *(float4*)(base + (size_t)(n0 + 2) * KD) = acc2;
    *(float4*)(base + (size_t)(n0 + 3) * KD) = acc3;
}

// ---------------- Kernel B: reduce partials, s = cx@W[n], squash, wv or out ----------------
// block = (group-of-4 b, n), 128 threads all active.
__global__ __launch_bounds__(NTHRB)
void kB(const float* __restrict__ cxp, const float* __restrict__ W_g,
        float* __restrict__ wv_g, float* __restrict__ out_g, int final_)
{
    __shared__ float w_s[KD * WSTR];       // 16.5 KB, padded [k][d]
    __shared__ float cxs[4 * KD];          // 2 KB
    __shared__ float vs_s[4][DC];

    const int t = threadIdx.x, blk = blockIdx.x;
    const int pb_n = blk & 31, pb_b0 = (blk >> 5) * 4;

    // stage W[n] with row pad 33 (scalar stores, <=2-way banks)
    for (int rep = 0; rep < 8; ++rep) {
        int v = t + rep * NTHRB;           // 0..1023
        int k = v >> 3, d0 = (v & 7) << 2;
        float4 w4 = *(const float4*)(W_g + (size_t)pb_n * KD * DC + (v << 2));
        float* dst = w_s + k * WSTR + d0;
        dst[0] = w4.x; dst[1] = w4.y; dst[2] = w4.z; dst[3] = w4.w;
    }
    // reduce cx partials: thread = (bsub, k4)
    {
        const int bsub = t >> 5, k4 = t & 31;
        float4 s4 = {0,0,0,0};
        const float* p = cxp + (((size_t)(pb_b0 + bsub) * NCH) * NC + pb_n) * KD + (k4 << 2);
        #pragma unroll
        for (int c2 = 0; c2 < NCH; ++c2) {
            float4 v4 = *(const float4*)(p + (size_t)c2 * NC * KD);
            s4.x += v4.x; s4.y += v4.y; s4.z += v4.z; s4.w += v4.w;
        }
        *(float4*)(cxs + bsub * KD + (k4 << 2)) = s4;
    }
    __syncthreads();

    // s[d] = cxs . W[:,d]; squash over d (32 lanes)
    const int bsub = t >> 5, d = t & 31;
    float s = 0.f;
    const float* crow = cxs + bsub * KD;
    for (int k = 0; k < KD; ++k) s += crow[k] * w_s[k * WSTR + d];
    float sn = s * s;
    #pragma unroll
    for (int off = 1; off < 32; off <<= 1) sn += __shfl_xor(sn, off, 64);
    const float vv = s * (sn / ((1.f + sn) * (sqrtf(sn) + 1e-8f)));

    if (final_) {
        out_g[((size_t)(pb_b0 + bsub) * NC + pb_n) * DC + d] = vv;
    } else {
        vs_s[bsub][d] = vv;
        __syncthreads();
        // wv[k] = W[k,:] . v  for all 4 b's; thread t owns k=t (conflict-free via WSTR)
        const int k = t;
        float a0 = 0.f, a1 = 0.f, a2 = 0.f, a3 = 0.f;
        #pragma unroll
        for (int dd = 0; dd < DC; ++dd) {
            const float wk = w_s[k * WSTR + dd];
            a0 += wk * vs_s[0][dd];
            a1 += wk * vs_s[1][dd];
            a2 += wk * vs_s[2][dd];
            a3 += wk * vs_s[3][dd];
        }
        size_t base = (((size_t)pb_b0 * NC) + pb_n) * KD + k;
        wv_g[base                      ] = a0;
        wv_g[base + 1 * (size_t)NC * KD] = a1;
        wv_g[base + 2 * (size_t)NC * KD] = a2;
        wv_g[base + 3 * (size_t)NC * KD] = a3;
    }
}

extern "C" void kernel_launch(void* const* d_in, const int* in_sizes, int n_in,
                              void* d_out, int out_size, void* d_ws, size_t ws_size,
                              hipStream_t stream) {
    const float* x  = (const float*)d_in[0];
    const float* W  = (const float*)d_in[1];
    const float* b0 = (const float*)d_in[2];
    float* out = (float*)d_out;

    float* cxp   = (float*)d_ws;                 // 8 MB
    float* wv    = cxp + CXP_SZ;                 // 1 MB
    float* bb_ws = wv + WV_SZ;                   // 4 MB

    // iter 0: softmax(b0) + cx
    kACX<<<NBLK, NTHR, 0, stream>>>(b0, x, nullptr, nullptr, cxp, 0, 0);
    kB  <<<NBLK, NTHRB, 0, stream>>>(cxp, W, wv, out, 0);
    // iter 1: uv+bb (persist) + softmax + cx
    kACX<<<NBLK, NTHR, 0, stream>>>(b0, x, wv, bb_ws, cxp, 1, 1);
    kB  <<<NBLK, NTHRB, 0, stream>>>(cxp, W, wv, out, 0);
    // iter 2: uv+bb + softmax + cx (bb not persisted)
    kACX<<<NBLK, NTHR, 0, stream>>>(bb_ws, x, wv, nullptr, cxp, 1, 0);
    kB  <<<NBLK, NTHRB, 0, stream>>>(cxp, W, wv, out, 1);
}